// Round 9
// baseline (63.663 us; speedup 1.0000x reference)
//
#include <hip/hip_runtime.h>
#include <math.h>

// Problem constants
#define LN 512
#define RN 4096
#define EN 32
#define FN 64

// Main tiling: 64(l) x 128(r) pair tile per block, 256 threads = 4 waves.
// Wave tile = 32(l) x 64(r) = 2x4 grid of 16x16 MFMA tiles.
// EHB=8 rbf steps per block -> grid (32,8,4) = 1024 blocks.
// NO LDS staging: fragments are loaded straight from global (f16 arrays are
// 18 MB = L3-resident; per-block-e tile is 32 KB = L1-resident across the
// block's waves). No __syncthreads() in the hot loop at all.
#define BLT 64
#define BRT 128
#define EHB 8

#define K16LOG2E 23.083120654223415f   // 16*log2(e):  exp(-16 t^2) = exp2(-K*t^2)
#define MU_STEP (8.0f / 31.0f)

typedef _Float16 half8 __attribute__((ext_vector_type(8)));  // MFMA A/B frag (4 VGPR)
typedef __attribute__((ext_vector_type(4))) float f32x4;     // MFMA C/D frag

// d_ws layout (bytes)
#define WS_LIG 0                      // 512*32*64*2  = 2 MB f16
#define WS_REC (2u * 1024 * 1024)     // 4096*32*64*2 = 16 MB f16
#define WS_PART (18u * 1024 * 1024)   // partials (1024 floats)

// ---------------- converter: plain fp32 -> f16 (RTE), linear layout ----------------
#define LELEM (LN * EN * FN)   // 1,048,576
#define RELEM (RN * EN * FN)   // 8,388,608

__global__ __launch_bounds__(256) void ff_convert(
    const float* __restrict__ lig_feat, const float* __restrict__ rec_feat,
    unsigned short* __restrict__ lig_h, unsigned short* __restrict__ rec_h)
{
    size_t idx = (size_t)blockIdx.x * 256 + threadIdx.x;   // 8 floats per thread
    const float* src;
    unsigned short* dst;
    if (idx < LELEM / 8) {
        src = lig_feat; dst = lig_h;
    } else {
        idx -= LELEM / 8;
        src = rec_feat; dst = rec_h;
    }
    const float4 v0 = *(const float4*)(src + idx * 8);
    const float4 v1 = *(const float4*)(src + idx * 8 + 4);
    const unsigned short q0 = __builtin_bit_cast(unsigned short, (_Float16)v0.x);
    const unsigned short q1 = __builtin_bit_cast(unsigned short, (_Float16)v0.y);
    const unsigned short q2 = __builtin_bit_cast(unsigned short, (_Float16)v0.z);
    const unsigned short q3 = __builtin_bit_cast(unsigned short, (_Float16)v0.w);
    const unsigned short q4 = __builtin_bit_cast(unsigned short, (_Float16)v1.x);
    const unsigned short q5 = __builtin_bit_cast(unsigned short, (_Float16)v1.y);
    const unsigned short q6 = __builtin_bit_cast(unsigned short, (_Float16)v1.z);
    const unsigned short q7 = __builtin_bit_cast(unsigned short, (_Float16)v1.w);
    uint4 o;
    o.x = (unsigned)q0 | ((unsigned)q1 << 16);
    o.y = (unsigned)q2 | ((unsigned)q3 << 16);
    o.z = (unsigned)q4 | ((unsigned)q5 << 16);
    o.w = (unsigned)q6 | ((unsigned)q7 << 16);
    *(uint4*)(dst + idx * 8) = o;
}

// ---------------- main kernel: barrier-free direct-from-global MFMA ----------------
__global__ __launch_bounds__(256, 1) void ff_mfma(
    const unsigned short* __restrict__ lig_h,   // [L][E][F] f16
    const unsigned short* __restrict__ rec_h,   // [R][E][F] f16
    const float* __restrict__ lig_coord,        // [L][3]
    const float* __restrict__ rec_coord,        // [R][3]
    float* __restrict__ partial)
{
    __shared__ float red[256];

    const int tid  = threadIdx.x;
    const int lane = tid & 63;
    const int w    = tid >> 6;         // 0..3
    const int wl   = (w & 1) * 2;      // wave's base l-tile (0,2) of 4
    const int wr   = (w >> 1) * 4;     // wave's base r-tile (0,4) of 8
    const int lrow = lane & 15;        // A-row / B-col within 16x16 tile
    const int lk   = lane >> 4;        // k-group 0..3

    const int l0 = blockIdx.y * BLT;
    const int r0 = blockIdx.x * BRT;
    const int e0 = blockIdx.z * EHB;

    // per-thread fragment byte offsets (int, < 2^25). Row stride = EN*FN*2 = 4096 B.
    // fragment granule for (kc,lk) = byte (kc*4+lk)*16 within the 128B e-slice.
    int voffA[2], voffB[4];
    #pragma unroll
    for (int ti = 0; ti < 2; ++ti) {
        const int arow = l0 + (wl + ti) * 16 + lrow;
        voffA[ti] = arow * 4096 + e0 * 128 + lk * 16;
    }
    #pragma unroll
    for (int tj = 0; tj < 4; ++tj) {
        const int brow = r0 + (wr + tj) * 16 + lrow;
        voffB[tj] = brow * 4096 + e0 * 128 + lk * 16;
    }
    const char* ligb = (const char*)lig_h;
    const char* recb = (const char*)rec_h;

    // ---- distances, computed once, reused for all EHB steps ----
    // C/D layout (m89-verified): col = lane&15 (-> r), row = (lane>>4)*4 + reg (-> l)
    float rcx[4], rcy[4], rcz[4];
    #pragma unroll
    for (int tj = 0; tj < 4; ++tj) {
        const int r = r0 + (wr + tj) * 16 + lrow;
        rcx[tj] = rec_coord[r * 3 + 0];
        rcy[tj] = rec_coord[r * 3 + 1];
        rcz[tj] = rec_coord[r * 3 + 2];
    }
    float d[2][4][4];   // [ti][tj][reg]
    #pragma unroll
    for (int ti = 0; ti < 2; ++ti) {
        #pragma unroll
        for (int i = 0; i < 4; ++i) {
            const int l = l0 + (wl + ti) * 16 + lk * 4 + i;
            const float lx = lig_coord[l * 3 + 0];
            const float ly = lig_coord[l * 3 + 1];
            const float lz = lig_coord[l * 3 + 2];
            #pragma unroll
            for (int tj = 0; tj < 4; ++tj) {
                const float dx = lx - rcx[tj];
                const float dy = ly - rcy[tj];
                const float dz = lz - rcz[tj];
                d[ti][tj][i] = sqrtf(fmaf(dx, dx, fmaf(dy, dy, dz * dz)));
            }
        }
    }

    float usum = 0.0f;

    #pragma unroll
    for (int ee = 0; ee < EHB; ++ee) {
        // ---- fragments straight from global; imm offset = kc*64 + ee*128 ----
        f32x4 acc[2][4];
        #pragma unroll
        for (int ti = 0; ti < 2; ++ti)
            #pragma unroll
            for (int tj = 0; tj < 4; ++tj)
                acc[ti][tj] = (f32x4){0.f, 0.f, 0.f, 0.f};

        #pragma unroll
        for (int kc = 0; kc < 2; ++kc) {
            const int imm = ee * 128 + kc * 64;
            half8 af[2], bf_[4];
            #pragma unroll
            for (int ti = 0; ti < 2; ++ti)
                af[ti] = *(const half8*)(ligb + voffA[ti] + imm);
            #pragma unroll
            for (int tj = 0; tj < 4; ++tj)
                bf_[tj] = *(const half8*)(recb + voffB[tj] + imm);
            #pragma unroll
            for (int ti = 0; ti < 2; ++ti) {
                #pragma unroll
                for (int tj = 0; tj < 4; ++tj) {
                    acc[ti][tj] = __builtin_amdgcn_mfma_f32_16x16x32_f16(
                        af[ti], bf_[tj], acc[ti][tj], 0, 0, 0);
                }
            }
        }

        // ---- rbf weight + accumulate ----
        const float mu = (float)(e0 + ee) * MU_STEP;
        #pragma unroll
        for (int ti = 0; ti < 2; ++ti) {
            #pragma unroll
            for (int tj = 0; tj < 4; ++tj) {
                #pragma unroll
                for (int i = 0; i < 4; ++i) {
                    const float t = d[ti][tj][i] - mu;
                    const float wgt = __builtin_amdgcn_exp2f(-K16LOG2E * t * t);
                    usum = fmaf(acc[ti][tj][i], wgt, usum);
                }
            }
        }
    }

    // ---- block reduction ----
    red[tid] = usum;
    __syncthreads();
    #pragma unroll
    for (int st = 128; st > 0; st >>= 1) {
        if (tid < st) red[tid] += red[tid + st];
        __syncthreads();
    }
    if (tid == 0) {
        const int bidx = (blockIdx.z * gridDim.y + blockIdx.y) * gridDim.x + blockIdx.x;
        partial[bidx] = red[0];
    }
}

__global__ __launch_bounds__(256) void ff_reduce(
    const float* __restrict__ partial, float* __restrict__ out, int n)
{
    __shared__ float s[256];
    float v = 0.0f;
    for (int i = threadIdx.x; i < n; i += 256) v += partial[i];
    s[threadIdx.x] = v;
    __syncthreads();
    #pragma unroll
    for (int st = 128; st > 0; st >>= 1) {
        if (threadIdx.x < st) s[threadIdx.x] += s[threadIdx.x + st];
        __syncthreads();
    }
    if (threadIdx.x == 0) out[0] = s[0] * 0.01f;
}

extern "C" void kernel_launch(void* const* d_in, const int* in_sizes, int n_in,
                              void* d_out, int out_size, void* d_ws, size_t ws_size,
                              hipStream_t stream)
{
    const float* lig_feat  = (const float*)d_in[0];
    const float* rec_feat  = (const float*)d_in[1];
    const float* lig_coord = (const float*)d_in[2];
    const float* rec_coord = (const float*)d_in[3];
    float* out = (float*)d_out;

    unsigned short* lig_h = (unsigned short*)((char*)d_ws + WS_LIG);
    unsigned short* rec_h = (unsigned short*)((char*)d_ws + WS_REC);
    float* partial        = (float*)((char*)d_ws + WS_PART);

    // 1) fp32 -> f16 cast of both feature arrays (plain layout)
    const int nThreads8 = (LELEM + RELEM) / 8;       // 1,179,648
    ff_convert<<<nThreads8 / 256, 256, 0, stream>>>(lig_feat, rec_feat, lig_h, rec_h);

    // 2) main MFMA kernel (no LDS staging, no barriers in hot loop)
    const dim3 grid(RN / BRT, LN / BLT, EN / EHB);   // (32, 8, 4) = 1024 blocks
    ff_mfma<<<grid, dim3(256), 0, stream>>>(lig_h, rec_h, lig_coord, rec_coord, partial);

    // 3) final reduction
    const int nPartial = (RN / BRT) * (LN / BLT) * (EN / EHB);   // 1024
    ff_reduce<<<1, 256, 0, stream>>>(partial, out, nPartial);
}

// Round 10
// 40.019 us; speedup vs baseline: 1.5908x; 1.5908x over previous
//
#include <hip/hip_runtime.h>
#include <math.h>

// Problem constants
#define LN 512
#define RN 4096
#define EN 32
#define FN 64

// Main tiling: 128(l) x 128(r) pair tile per block, 512 threads = 8 waves.
// Wave tile = 32(l) x 64(r) = 2x4 grid of 16x16 MFMA tiles.
// EH=8 -> grid (32,4,4) = 512 blocks = 2 blocks/CU (LDS-capped: 64KB dbuf).
// Double-buffered LDS, T3 minimum-2-phase: issue next-e stage BEFORE compute,
// one __syncthreads per e (its auto vmcnt(0) waits on loads that flew over
// the whole compute phase).
#define BLT 128
#define BRT 128
#define EH  8

#define K16LOG2E 23.083120654223415f   // 16*log2(e):  exp(-16 t^2) = exp2(-K*t^2)
#define MU_STEP (8.0f / 31.0f)

typedef _Float16 half8 __attribute__((ext_vector_type(8)));  // MFMA A/B frag (4 VGPR)
typedef __attribute__((ext_vector_type(4))) float f32x4;     // MFMA C/D frag

// LDS: 2 buffers, each = A plane (128 rows x 128B) + B plane (128 rows x 128B)
#define BUFBYTES 32768
#define BPLANE   16384

// d_ws layout (bytes)
#define WS_LIG 0                      // 512*32*64*2  = 2 MB f16 swizzled
#define WS_REC (2u * 1024 * 1024)     // 4096*32*64*2 = 16 MB f16 swizzled
#define WS_PART (18u * 1024 * 1024)   // partials (512 floats)

// 16-byte granules per feature row: FN*2/16 = 8.  Row stride = EN*128 = 4096 B.
#define LCHUNKS (LN * EN * 8)   // 131072
#define RCHUNKS (RN * EN * 8)   // 1048576

typedef const __attribute__((address_space(1))) unsigned int* gas_ptr;
typedef __attribute__((address_space(3))) unsigned int* las_ptr;
#define GL16(g, l) __builtin_amdgcn_global_load_lds((gas_ptr)(g), (las_ptr)(l), 16, 0, 0)

// ---------------- converter: fp32 -> f16 (RTE), granule-XOR pre-swizzle ----------------
// Granule at ((row*EN+e)*8 + (gf ^ (row&7)))*16B holds f16 of f = gf*8..gf*8+7.
// A linear 128-row copy into LDS then reproduces the in-LDS XOR-swizzled layout
// (verified round 8: absmax 0.0625, conflicts 0).
__global__ __launch_bounds__(256) void ff_convert(
    const float* __restrict__ lig_feat, const float* __restrict__ rec_feat,
    unsigned short* __restrict__ lig_swz, unsigned short* __restrict__ rec_swz)
{
    int idx = blockIdx.x * 256 + threadIdx.x;
    const float* src;
    unsigned short* dst;
    if (idx < LCHUNKS) {
        src = lig_feat; dst = lig_swz;
    } else {
        idx -= LCHUNKS;
        src = rec_feat; dst = rec_swz;
    }
    const int row = idx >> 8;         // 256 granules per row (EN*8)
    const int e   = (idx >> 3) & 31;
    const int gf  = idx & 7;

    const float* s = src + (((size_t)row * EN + e) * FN + gf * 8);
    const float4 v0 = *(const float4*)s;
    const float4 v1 = *(const float4*)(s + 4);

    const unsigned short q0 = __builtin_bit_cast(unsigned short, (_Float16)v0.x);
    const unsigned short q1 = __builtin_bit_cast(unsigned short, (_Float16)v0.y);
    const unsigned short q2 = __builtin_bit_cast(unsigned short, (_Float16)v0.z);
    const unsigned short q3 = __builtin_bit_cast(unsigned short, (_Float16)v0.w);
    const unsigned short q4 = __builtin_bit_cast(unsigned short, (_Float16)v1.x);
    const unsigned short q5 = __builtin_bit_cast(unsigned short, (_Float16)v1.y);
    const unsigned short q6 = __builtin_bit_cast(unsigned short, (_Float16)v1.z);
    const unsigned short q7 = __builtin_bit_cast(unsigned short, (_Float16)v1.w);
    uint4 o;
    o.x = (unsigned)q0 | ((unsigned)q1 << 16);
    o.y = (unsigned)q2 | ((unsigned)q3 << 16);
    o.z = (unsigned)q4 | ((unsigned)q5 << 16);
    o.w = (unsigned)q6 | ((unsigned)q7 << 16);

    const size_t dpos = (((size_t)row * EN + e) * 8 + (gf ^ (row & 7))) * 8; // ushort units
    *(uint4*)(dst + dpos) = o;
}

// ---------------- main kernel: double-buffered GL16 + MFMA ----------------
__global__ __launch_bounds__(512, 1) void ff_mfma(
    const unsigned short* __restrict__ lig_swz,  // [L][E][8 swz granules][8 f16]
    const unsigned short* __restrict__ rec_swz,  // [R][E][8 swz granules][8 f16]
    const float* __restrict__ lig_coord,         // [L][3]
    const float* __restrict__ rec_coord,         // [R][3]
    float* __restrict__ partial)
{
    __shared__ char lds[2 * BUFBYTES];

    const int tid  = threadIdx.x;
    const int lane = tid & 63;
    const int w    = tid >> 6;         // 0..7
    const int wl   = (w & 3) * 2;      // wave's base l-tile (0,2,4,6) of 8
    const int wr   = (w >> 2) * 4;     // wave's base r-tile (0,4) of 8
    const int lrow = lane & 15;        // A-row / B-col within 16x16 tile
    const int lk   = lane >> 4;        // k-group 0..3

    const int l0 = blockIdx.y * BLT;
    const int r0 = blockIdx.x * BRT;
    const int e0 = blockIdx.z * EH;

    // per-thread staging source offsets (hoisted): granule idx = k*512+tid,
    // row = idx>>3, g = idx&7 -> byte = row*4096 + g*16  (+ e*128 per step)
    int soff[2];
    #pragma unroll
    for (int k = 0; k < 2; ++k) {
        const int idx = k * 512 + tid;
        soff[k] = (idx >> 3) * (EN * 128) + (idx & 7) * 16;
    }
    const char* ligb = (const char*)lig_swz + (size_t)l0 * (EN * 128);
    const char* recb = (const char*)rec_swz + (size_t)r0 * (EN * 128);

#define STAGE(b, e_) do {                                                   \
        const int ebyte_ = (e_) * 128;                                      \
        _Pragma("unroll")                                                   \
        for (int k_ = 0; k_ < 2; ++k_) {                                    \
            const int idx_ = k_ * 512 + tid;                                \
            GL16(ligb + soff[k_] + ebyte_, lds + (b) * BUFBYTES + idx_ * 16);            \
            GL16(recb + soff[k_] + ebyte_, lds + (b) * BUFBYTES + BPLANE + idx_ * 16);   \
        }                                                                   \
    } while (0)

    // ---- distances, computed once, reused for all EH steps ----
    // C/D layout (m89-verified): col = lane&15 (-> r), row = (lane>>4)*4 + reg (-> l)
    float rcx[4], rcy[4], rcz[4];
    #pragma unroll
    for (int tj = 0; tj < 4; ++tj) {
        const int r = r0 + (wr + tj) * 16 + lrow;
        rcx[tj] = rec_coord[r * 3 + 0];
        rcy[tj] = rec_coord[r * 3 + 1];
        rcz[tj] = rec_coord[r * 3 + 2];
    }
    float d[2][4][4];   // [ti][tj][reg]
    #pragma unroll
    for (int ti = 0; ti < 2; ++ti) {
        #pragma unroll
        for (int i = 0; i < 4; ++i) {
            const int l = l0 + (wl + ti) * 16 + lk * 4 + i;
            const float lx = lig_coord[l * 3 + 0];
            const float ly = lig_coord[l * 3 + 1];
            const float lz = lig_coord[l * 3 + 2];
            #pragma unroll
            for (int tj = 0; tj < 4; ++tj) {
                const float dx = lx - rcx[tj];
                const float dy = ly - rcy[tj];
                const float dz = lz - rcz[tj];
                d[ti][tj][i] = sqrtf(fmaf(dx, dx, fmaf(dy, dy, dz * dz)));
            }
        }
    }

    // ---- pipeline prologue: stage e0 into buf0 ----
    STAGE(0, e0);
    __syncthreads();   // auto vmcnt(0): buf0 valid

    float usum = 0.0f;

    for (int ee = 0; ee < EH; ++ee) {
        const int cur = ee & 1;
        const int e   = e0 + ee;

        // ---- issue next-e stage into the other buffer (flies over compute) ----
        if (ee + 1 < EH) STAGE(cur ^ 1, e + 1);

        // ---- compute from buf[cur] ----
        const char* base = lds + cur * BUFBYTES;

        f32x4 acc[2][4];
        #pragma unroll
        for (int ti = 0; ti < 2; ++ti)
            #pragma unroll
            for (int tj = 0; tj < 4; ++tj)
                acc[ti][tj] = (f32x4){0.f, 0.f, 0.f, 0.f};

        #pragma unroll
        for (int kc = 0; kc < 2; ++kc) {
            const int inrow = (kc * 64 + lk * 16) ^ ((lrow & 7) << 4);
            half8 af[2], bf_[4];
            #pragma unroll
            for (int t = 0; t < 2; ++t) {
                const int arow = (wl + t) * 16 + lrow;
                af[t] = *(const half8*)(base + arow * 128 + inrow);
            }
            #pragma unroll
            for (int t = 0; t < 4; ++t) {
                const int brow = (wr + t) * 16 + lrow;
                bf_[t] = *(const half8*)(base + BPLANE + brow * 128 + inrow);
            }
            #pragma unroll
            for (int ti = 0; ti < 2; ++ti) {
                #pragma unroll
                for (int tj = 0; tj < 4; ++tj) {
                    acc[ti][tj] = __builtin_amdgcn_mfma_f32_16x16x32_f16(
                        af[ti], bf_[tj], acc[ti][tj], 0, 0, 0);
                }
            }
        }

        // ---- rbf weight + accumulate ----
        const float mu = (float)e * MU_STEP;
        #pragma unroll
        for (int ti = 0; ti < 2; ++ti) {
            #pragma unroll
            for (int tj = 0; tj < 4; ++tj) {
                #pragma unroll
                for (int i = 0; i < 4; ++i) {
                    const float t = d[ti][tj][i] - mu;
                    const float wgt = __builtin_amdgcn_exp2f(-K16LOG2E * t * t);
                    usum = fmaf(acc[ti][tj][i], wgt, usum);
                }
            }
        }

        // one barrier per e: drains this iter's stage loads (they flew over the
        // compute above) and ensures all waves finished reading buf[cur] before
        // the next iteration's STAGE overwrites it.
        __syncthreads();
    }

    // ---- block reduction (reuse LDS; safe after the loop's final barrier) ----
    float* red = (float*)lds;
    red[tid] = usum;
    __syncthreads();
    #pragma unroll
    for (int st = 256; st > 0; st >>= 1) {
        if (tid < st) red[tid] += red[tid + st];
        __syncthreads();
    }
    if (tid == 0) {
        const int bidx = (blockIdx.z * gridDim.y + blockIdx.y) * gridDim.x + blockIdx.x;
        partial[bidx] = red[0];
    }
#undef STAGE
}

__global__ __launch_bounds__(256) void ff_reduce(
    const float* __restrict__ partial, float* __restrict__ out, int n)
{
    __shared__ float s[256];
    float v = 0.0f;
    for (int i = threadIdx.x; i < n; i += 256) v += partial[i];
    s[threadIdx.x] = v;
    __syncthreads();
    #pragma unroll
    for (int st = 128; st > 0; st >>= 1) {
        if (threadIdx.x < st) s[threadIdx.x] += s[threadIdx.x + st];
        __syncthreads();
    }
    if (threadIdx.x == 0) out[0] = s[0] * 0.01f;
}

extern "C" void kernel_launch(void* const* d_in, const int* in_sizes, int n_in,
                              void* d_out, int out_size, void* d_ws, size_t ws_size,
                              hipStream_t stream)
{
    const float* lig_feat  = (const float*)d_in[0];
    const float* rec_feat  = (const float*)d_in[1];
    const float* lig_coord = (const float*)d_in[2];
    const float* rec_coord = (const float*)d_in[3];
    float* out = (float*)d_out;

    unsigned short* lig_swz = (unsigned short*)((char*)d_ws + WS_LIG);
    unsigned short* rec_swz = (unsigned short*)((char*)d_ws + WS_REC);
    float* partial          = (float*)((char*)d_ws + WS_PART);

    // 1) one-time fp32 -> swizzled f16 conversion (BW-floor ~9 us)
    const int nChunks = LCHUNKS + RCHUNKS;           // 1,179,648
    ff_convert<<<nChunks / 256, 256, 0, stream>>>(lig_feat, rec_feat, lig_swz, rec_swz);

    // 2) main MFMA kernel, double-buffered pipeline
    const dim3 grid(RN / BRT, LN / BLT, EN / EH);    // (32, 4, 4) = 512 blocks
    ff_mfma<<<grid, dim3(512), 0, stream>>>(lig_swz, rec_swz, lig_coord, rec_coord, partial);

    // 3) final reduction
    const int nPartial = (RN / BRT) * (LN / BLT) * (EN / EH);   // 512
    ff_reduce<<<1, 256, 0, stream>>>(partial, out, nPartial);
}